// Round 7
// baseline (313.899 us; speedup 1.0000x reference)
//
#include <hip/hip_runtime.h>
#include <math.h>

typedef unsigned long long u64;

#define N_PTS 16384
#define HALF_N 8192
#define KK 16
#define NK (N_PTS * KK)
#define EPSV 1e-5f

// ---- KNN config: 16 queries/block, 2 half-range blocks per query group ----
#define QPB 16
#define SHARDS 16
#define NSPLIT 2
#define SEGC (HALF_N / NSPLIT)   // 4096 candidates per block
#define MCAND (SEGC / SHARDS)    // 256 candidates per shard
#define CHUNK 4
#define BCAP 9
#define BSTRIDE 9                // lane buffer stride (u64)
#define FTHRESH 6                // post-check cnt<=5, +4/chunk -> <=9 = BCAP

// ---- workspace layout (bytes) ----
#define OFF_IDX   0u                           // int32 [N_PTS][KK]         = 1 MB
#define OFF_PC    (1u << 20)                   // float4 [N_PTS]            = 256 KB
#define OFF_MA    (OFF_PC + N_PTS * 16u)       // m0 [N][16] / m3 low / knntmp
#define OFF_MB    (OFF_MA + N_PTS * 16u * 4u)  // m1 [N][16] / m3 high / knntmp
#define OFF_MC    (OFF_MB + N_PTS * 16u * 4u)  // m2 [N][32] / knntmp       = 2 MB
#define OFF_PART  (OFF_MC + N_PTS * 32u * 4u)  // float [1024][64]          = 256 KB
#define OFF_STATS (OFF_PART + 1024u * 64u * 4u)// float [4][64]
// knntmp (u64 [N_PTS][NSPLIT][16] = 4 MB) overlays MA|MB|MC (dead during KNN)

// ---------------- prep: pack (x,y,z,d2) ----------------
__global__ __launch_bounds__(256) void prep_kernel(const float* __restrict__ pts,
                                                   float4* __restrict__ pc) {
    int i = blockIdx.x * 256 + threadIdx.x;
    float x = pts[i * 5 + 1], y = pts[i * 5 + 2], z = pts[i * 5 + 3];
    float d2 = __fadd_rn(__fadd_rn(__fmul_rn(x, x), __fmul_rn(y, y)), __fmul_rn(z, z));
    pc[i] = make_float4(x, y, z, d2);
}

// ---------------- branch-free sorting primitives on u64 keys ----------------
__device__ __forceinline__ void ce64(u64& a, u64& b) {
    bool c = b < a;
    u64 t = c ? b : a;
    b = c ? a : b;
    a = t;
}

// sort 8 ascending (Batcher odd-even mergesort, 19 CE)
__device__ __forceinline__ void sort8(u64* b) {
    ce64(b[0], b[1]); ce64(b[2], b[3]); ce64(b[4], b[5]); ce64(b[6], b[7]);
    ce64(b[0], b[2]); ce64(b[1], b[3]); ce64(b[4], b[6]); ce64(b[5], b[7]);
    ce64(b[1], b[2]); ce64(b[5], b[6]);
    ce64(b[0], b[4]); ce64(b[1], b[5]); ce64(b[2], b[6]); ce64(b[3], b[7]);
    ce64(b[2], b[4]); ce64(b[3], b[5]);
    ce64(b[1], b[2]); ce64(b[3], b[4]); ce64(b[5], b[6]);
}

// sort 16 ascending: two sort8 + bitonic merge
__device__ __forceinline__ void sort16(u64 b[16]) {
    sort8(b); sort8(b + 8);
#pragma unroll
    for (int j = 0; j < 8; ++j) ce64(b[j], b[15 - j]);
#pragma unroll
    for (int h = 0; h < 16; h += 8) {
        ce64(b[h + 0], b[h + 4]); ce64(b[h + 1], b[h + 5]);
        ce64(b[h + 2], b[h + 6]); ce64(b[h + 3], b[h + 7]);
        ce64(b[h + 0], b[h + 2]); ce64(b[h + 1], b[h + 3]);
        ce64(b[h + 4], b[h + 6]); ce64(b[h + 5], b[h + 7]);
        ce64(b[h + 0], b[h + 1]); ce64(b[h + 2], b[h + 3]);
        ce64(b[h + 4], b[h + 5]); ce64(b[h + 6], b[h + 7]);
    }
}

// merge two ascending 16-lists, keep smallest 16 ascending in L (B clobbered)
__device__ __forceinline__ void merge16(u64 L[16], u64 B[16]) {
#pragma unroll
    for (int j = 0; j < 8; ++j) {
        u64 a0 = L[j],      b0 = B[15 - j];
        u64 a1 = L[15 - j], b1 = B[j];
        B[j]      = a0 < b0 ? a0 : b0;
        B[15 - j] = a1 < b1 ? a1 : b1;
    }
#pragma unroll
    for (int s = 8; s >= 1; s >>= 1) {
#pragma unroll
        for (int j = 0; j < 16; ++j)
            if (!(j & s)) ce64(B[j], B[j + s]);
    }
#pragma unroll
    for (int j = 0; j < 16; ++j) L[j] = B[j];
}

// monotone key transform helpers (float bits <-> sortable uint)
__device__ __forceinline__ unsigned fkey(unsigned u) {
    return u ^ ((unsigned)(((int)u) >> 31) | 0x80000000u);
}
__device__ __forceinline__ unsigned fkey_inv(unsigned k32) {
    unsigned xv = 0x80000000u | ((~((unsigned)(((int)k32) >> 31))) >> 1);
    return k32 ^ xv; // sentinel 0xFFFFFFFF -> 0x7FFFFFFF (uint > +inf bits)
}

// flush buffered raw (floatbits<<32|idx) entries: transform to monotone keys,
// sort (pad to 16), merge into L. Returns float-BITS of new 16th-best dist.
__device__ __forceinline__ unsigned flush16(u64 L[16], const u64* buf, int& cnt) {
    u64 b[16];
#pragma unroll
    for (int e = 0; e < 16; ++e) {
        u64 raw = (e < BCAP) ? buf[e] : 0ULL;
        u64 key = ((u64)fkey((unsigned)(raw >> 32)) << 32) | (raw & 0xffffffffULL);
        b[e] = (e < cnt) ? key : ~0ULL;
    }
    cnt = 0;
    sort16(b);
    merge16(L, b);
    return fkey_inv((unsigned)(L[15] >> 32));
}

// -------- exact KNN pass 1: per (query, half) sorted top-16 key list --------
// tau shared per query within the block: min over 16 shards of each shard's
// current 16th-best dist (float bits; dists >= 0 so uint order == float order).
// Rejecting dist > tau is exact: >=16 candidates in this half are <= tau.
__global__ __launch_bounds__(256, 4) void knn_scan(const float4* __restrict__ pc,
                                                   u64* __restrict__ tmp) {
    // [0, 256*9) u64 lane buffers; tree phase reuses [0, 128*17) u64
    __shared__ u64 smem[256 * BSTRIDE]; // 18,432 B -> 8 blocks/CU
    __shared__ unsigned tauS[QPB];

    const int tid = threadIdx.x;
    const int q = tid & (QPB - 1);
    const int s = tid >> 4;
    const int bq = blockIdx.x >> 1;
    const int half = blockIdx.x & 1;
    const int n = bq * QPB + q;
    const int base = ((n >= HALF_N) ? HALF_N : 0) + half * SEGC;
    const float4 p = pc[n];

    if (tid < QPB) tauS[tid] = 0x7f800000u; // +inf bits
    __syncthreads();

    u64* buf = &smem[tid * BSTRIDE];
    int cnt = 0;
    const int c0 = base + s * MCAND;

    // ---- seed: exact sorted top-16 of the shard's first 16 candidates ----
    u64 L[16];
#pragma unroll
    for (int j = 0; j < 16; ++j) {
        const int ci = c0 + j;
        const float4 cp = pc[ci];
        float dot = __fadd_rn(__fadd_rn(__fmul_rn(p.x, cp.x), __fmul_rn(p.y, cp.y)),
                              __fmul_rn(p.z, cp.z));
        float dist = __fsub_rn(__fadd_rn(p.w, cp.w), __fmul_rn(2.0f, dot));
        L[j] = ((u64)fkey(__float_as_uint(dist)) << 32) | (unsigned)ci;
    }
    sort16(L);
    atomicMin(&tauS[q], fkey_inv((unsigned)(L[15] >> 32)));
    __syncthreads(); // all seed taus visible

    // ---- main scan ----
#pragma unroll 1
    for (int t0 = 16; t0 < MCAND; t0 += CHUNK) {
        const float tauf = __uint_as_float(((volatile unsigned*)tauS)[q]);
#pragma unroll
        for (int dt = 0; dt < CHUNK; ++dt) {
            const int ci = c0 + t0 + dt;
            const float4 cp = pc[ci]; // uniform per 16-lane group -> broadcast
            float dot = __fadd_rn(__fadd_rn(__fmul_rn(p.x, cp.x), __fmul_rn(p.y, cp.y)),
                                  __fmul_rn(p.z, cp.z));
            float dist = __fsub_rn(__fadd_rn(p.w, cp.w), __fmul_rn(2.0f, dot));
            if (!(dist > tauf)) { // ties admitted; exact select at flush
                buf[cnt] = ((u64)__float_as_uint(dist) << 32) | (unsigned)ci;
                ++cnt;
            }
        }
        if (__any(cnt >= FTHRESH)) {
            unsigned tb = flush16(L, buf, cnt);
            atomicMin(&tauS[q], tb);
        }
    }
    flush16(L, buf, cnt);

    // ---- cross-shard merge tree (writer-half lists staged in reused smem) ----
    __syncthreads(); // buffers dead
    for (int step = SHARDS / 2; step >= 1; step >>= 1) {
        if (s >= step && s < 2 * step) {
#pragma unroll
            for (int j = 0; j < 16; ++j) smem[((s - step) * QPB + q) * 17 + j] = L[j];
        }
        __syncthreads();
        if (s < step) {
            u64 B[16];
#pragma unroll
            for (int j = 0; j < 16; ++j) B[j] = smem[(s * QPB + q) * 17 + j];
            merge16(L, B);
        }
        __syncthreads();
    }

    if (s == 0) {
#pragma unroll
        for (int j = 0; j < 16; ++j) tmp[(n * NSPLIT + half) * 16 + j] = L[j];
    }
}

// -------- exact KNN pass 2: merge the two half-lists per query --------
__global__ __launch_bounds__(256) void knn_merge(const u64* __restrict__ tmp,
                                                 int* __restrict__ idx) {
    const int n = blockIdx.x * 256 + threadIdx.x;
    u64 L[16], B[16];
#pragma unroll
    for (int j = 0; j < 16; ++j) L[j] = tmp[(n * NSPLIT + 0) * 16 + j];
#pragma unroll
    for (int j = 0; j < 16; ++j) B[j] = tmp[(n * NSPLIT + 1) * 16 + j];
    merge16(L, B);
#pragma unroll
    for (int j = 0; j < 16; ++j) idx[n * KK + j] = (int)(L[j] & 0xffffffffULL);
}

// ============ per-layer conv: h once -> {part sums, raw per-point max} ============
// MODE 0: xin = pts (stride 5, offset 1, raw). MODE 1: xin = m_prev, apply
// relu(fma(., A, B2)) of the PREVIOUS layer on the fly (A>0, so
// max-then-affine == affine-then-max; relu monotone).
template <int IN_C, int OUT_C, int MODE>
__global__ __launch_bounds__(256) void convS_kernel(const float* __restrict__ xin,
                                                    const float* __restrict__ statsPrev,
                                                    const int* __restrict__ idxg,
                                                    const float* __restrict__ W,
                                                    const float* __restrict__ bb,
                                                    float* __restrict__ part,
                                                    float* __restrict__ mout) {
    constexpr int RED = 256 / OUT_C;
    __shared__ float hbuf[OUT_C][257];
    __shared__ float pr1[OUT_C][RED + 1];
    __shared__ float pr2[OUT_C][RED + 1];
    __shared__ float2 sAB[IN_C];

    const int tid = threadIdx.x;
    const int gt = blockIdx.x * 256 + tid;
    const int n = gt >> 4;

    if (MODE == 1) {
        if (tid < IN_C) sAB[tid] = make_float2(statsPrev[tid], statsPrev[32 + tid]);
        __syncthreads();
    }

    float xn[IN_C], dx[IN_C];
    const int j = idxg[gt];
    if (MODE == 0) {
        const float* rn = xin + n * 5 + 1;
        const float* rj = xin + j * 5 + 1;
#pragma unroll
        for (int e = 0; e < IN_C; ++e) xn[e] = rn[e];
#pragma unroll
        for (int e = 0; e < IN_C; ++e) dx[e] = rj[e] - xn[e];
    } else {
        const float4* rn = (const float4*)(xin + n * IN_C);
        const float4* rj = (const float4*)(xin + j * IN_C);
#pragma unroll
        for (int e4 = 0; e4 < IN_C / 4; ++e4) {
            float4 a = rn[e4];
            float4 bq = rj[e4];
            float av[4] = {a.x, a.y, a.z, a.w};
            float bv[4] = {bq.x, bq.y, bq.z, bq.w};
#pragma unroll
            for (int u = 0; u < 4; ++u) {
                float2 ab = sAB[4 * e4 + u];
                float xv = fmaxf(fmaf(av[u], ab.x, ab.y), 0.f);
                float jv = fmaxf(fmaf(bv[u], ab.x, ab.y), 0.f);
                xn[4 * e4 + u] = xv;
                dx[4 * e4 + u] = jv - xv;
            }
        }
    }

    float h[OUT_C];
#pragma unroll
    for (int c = 0; c < OUT_C; ++c) {
        float acc = bb[c];
#pragma unroll
        for (int e = 0; e < IN_C; ++e) acc = fmaf(W[c * 2 * IN_C + e], xn[e], acc);
#pragma unroll
        for (int e = 0; e < IN_C; ++e) acc = fmaf(W[c * 2 * IN_C + IN_C + e], dx[e], acc);
        h[c] = acc;
    }

    // ---- stage h to LDS once; sums and max both read from hbuf ----
#pragma unroll
    for (int c = 0; c < OUT_C; ++c) hbuf[c][tid] = h[c];
    __syncthreads();
    {
        const int c2 = tid & (OUT_C - 1);
        const int ch = tid / OUT_C;
        float s1 = 0.f, s2 = 0.f;
#pragma unroll
        for (int i = 0; i < OUT_C; ++i) {
            float hh = hbuf[c2][ch * OUT_C + i];
            s1 += hh; s2 += hh * hh;
        }
        pr1[c2][ch] = s1;
        pr2[c2][ch] = s2;
    }
    __syncthreads();
    if (tid < OUT_C) {
        float t1 = 0.f, t2 = 0.f;
#pragma unroll
        for (int k = 0; k < RED; ++k) { t1 += pr1[tid][k]; t2 += pr2[tid][k]; }
        part[blockIdx.x * 64 + tid]      = t1;
        part[blockIdx.x * 64 + 32 + tid] = t2;
    }

    // ---- raw max over K=16 from hbuf: one thread per (n_local, c) ----
    {
        const int n0 = blockIdx.x * 16;
        constexpr int ITER = OUT_C / 16;
#pragma unroll
        for (int r = 0; r < ITER; ++r) {
            const int c = tid & (OUT_C - 1);
            const int nl = (tid / OUT_C) + r * (256 / OUT_C);
            float m = hbuf[c][nl * 16];
#pragma unroll
            for (int k = 1; k < 16; ++k) m = fmaxf(m, hbuf[c][nl * 16 + k]);
            mout[(n0 + nl) * OUT_C + c] = m;
        }
    }
}

// ---------------- finalize: part -> A[c]=rs*g, B2[c]=t-mu*A ----------------
template <int OUT_C>
__global__ __launch_bounds__(256) void finalize_kernel(const float* __restrict__ part,
                                                       const float* __restrict__ g,
                                                       const float* __restrict__ t,
                                                       float* __restrict__ statsL) {
    __shared__ float red[4][64];
    __shared__ float tot[64];
    const int tid = threadIdx.x;
    const int c2 = tid & 63, ch = tid >> 6;
    float s = 0.f;
    for (int bk = ch * 256; bk < ch * 256 + 256; ++bk) s += part[bk * 64 + c2];
    red[ch][c2] = s;
    __syncthreads();
    if (tid < 64) tot[tid] = red[0][tid] + red[1][tid] + red[2][tid] + red[3][tid];
    __syncthreads();
    if (tid < OUT_C) {
        const float inv = 1.0f / (float)NK;
        float mu  = tot[tid] * inv;
        float var = tot[32 + tid] * inv - mu * mu;
        float rs  = 1.0f / sqrtf(var + EPSV);
        float A   = rs * g[tid];
        statsL[tid]      = A;
        statsL[32 + tid] = t[tid] - mu * A;
    }
}

// ---- fused finalize(layer3) + apply: every block redundantly reduces part
// (deterministic fixed order), then applies relu(affine(m3)) to its slice ----
__global__ __launch_bounds__(256) void finapply_kernel(const float* __restrict__ part,
                                                       const float* __restrict__ g,
                                                       const float* __restrict__ t,
                                                       const float* __restrict__ m,
                                                       float* __restrict__ out) {
    __shared__ float red[4][64];
    __shared__ float tot[64];
    __shared__ float sA[32], sB[32];
    const int tid = threadIdx.x;
    const int c2 = tid & 63, ch = tid >> 6;
    float s = 0.f;
    for (int bk = ch * 256; bk < ch * 256 + 256; ++bk) s += part[bk * 64 + c2];
    red[ch][c2] = s;
    __syncthreads();
    if (tid < 64) tot[tid] = red[0][tid] + red[1][tid] + red[2][tid] + red[3][tid];
    __syncthreads();
    if (tid < 32) {
        const float inv = 1.0f / (float)NK;
        float mu  = tot[tid] * inv;
        float var = tot[32 + tid] * inv - mu * mu;
        float rs  = 1.0f / sqrtf(var + EPSV);
        float A   = rs * g[tid];
        sA[tid] = A;
        sB[tid] = t[tid] - mu * A;
    }
    __syncthreads();
    const int base = blockIdx.x * 2048 + tid;
#pragma unroll
    for (int r = 0; r < 8; ++r) {
        const int i = base + r * 256;
        float4 mv = ((const float4*)m)[i];
        const int c0 = (i * 4) & 31;
        float4 o;
        o.x = fmaxf(fmaf(mv.x, sA[c0 + 0], sB[c0 + 0]), 0.f);
        o.y = fmaxf(fmaf(mv.y, sA[c0 + 1], sB[c0 + 1]), 0.f);
        o.z = fmaxf(fmaf(mv.z, sA[c0 + 2], sB[c0 + 2]), 0.f);
        o.w = fmaxf(fmaf(mv.w, sA[c0 + 3], sB[c0 + 3]), 0.f);
        ((float4*)out)[i] = o;
    }
}

extern "C" void kernel_launch(void* const* d_in, const int* in_sizes, int n_in,
                              void* d_out, int out_size, void* d_ws, size_t ws_size,
                              hipStream_t stream) {
    const float* pts = (const float*)d_in[0];
    const float* Wl[4], *bl[4], *gl[4], *tl[4];
    for (int l = 0; l < 4; ++l) {
        Wl[l] = (const float*)d_in[1 + 4 * l + 0];
        bl[l] = (const float*)d_in[1 + 4 * l + 1];
        gl[l] = (const float*)d_in[1 + 4 * l + 2];
        tl[l] = (const float*)d_in[1 + 4 * l + 3];
    }
    char* ws = (char*)d_ws;
    int*    idx   = (int*)(ws + OFF_IDX);
    float4* pc    = (float4*)(ws + OFF_PC);
    u64*    knntmp= (u64*)(ws + OFF_MA);   // 4 MB, overlays m0|m1|m2 (dead in KNN phase)
    float*  m0    = (float*)(ws + OFF_MA); // [N][16]
    float*  m1    = (float*)(ws + OFF_MB); // [N][16]
    float*  m2    = (float*)(ws + OFF_MC); // [N][32]
    float*  m3    = (float*)(ws + OFF_MA); // [N][32] reuses MA|MB (m0,m1 dead)
    float*  part  = (float*)(ws + OFF_PART);
    float*  stats = (float*)(ws + OFF_STATS); // [4][64]
    float*  out   = (float*)d_out;

    prep_kernel<<<N_PTS / 256, 256, 0, stream>>>(pts, pc);
    knn_scan<<<(N_PTS / QPB) * NSPLIT, 256, 0, stream>>>(pc, knntmp);
    knn_merge<<<N_PTS / 256, 256, 0, stream>>>(knntmp, idx);

    const int GA = NK / 256; // 1024 blocks

    // layer 0: 4 -> 16 (raw pts input)
    convS_kernel<4, 16, 0><<<GA, 256, 0, stream>>>(pts, nullptr, idx, Wl[0], bl[0], part, m0);
    finalize_kernel<16><<<1, 256, 0, stream>>>(part, gl[0], tl[0], stats + 0);

    // layer 1: 16 -> 16 (m0 + layer-0 affine on the fly)
    convS_kernel<16, 16, 1><<<GA, 256, 0, stream>>>(m0, stats + 0, idx, Wl[1], bl[1], part, m1);
    finalize_kernel<16><<<1, 256, 0, stream>>>(part, gl[1], tl[1], stats + 64);

    // layer 2: 16 -> 32
    convS_kernel<16, 32, 1><<<GA, 256, 0, stream>>>(m1, stats + 64, idx, Wl[2], bl[2], part, m2);
    finalize_kernel<32><<<1, 256, 0, stream>>>(part, gl[2], tl[2], stats + 128);

    // layer 3: 32 -> 32 (writes m3 over MA|MB; m0/m1 dead)
    convS_kernel<32, 32, 1><<<GA, 256, 0, stream>>>(m2, stats + 128, idx, Wl[3], bl[3], part, m3);

    // fused finalize(layer3) + out = relu(affine(m3))
    finapply_kernel<<<64, 256, 0, stream>>>(part, gl[3], tl[3], m3, out);
}

// Round 8
// 238.198 us; speedup vs baseline: 1.3178x; 1.3178x over previous
//
#include <hip/hip_runtime.h>
#include <math.h>

typedef unsigned long long u64;

#define N_PTS 16384
#define HALF_N 8192
#define KK 16
#define NK (N_PTS * KK)
#define EPSV 1e-5f

// ---- KNN config: 16 queries x 16 shards per 256-thread block ----
#define QPB 16
#define SHARDS 16
#define MCAND (HALF_N / SHARDS) // 512 candidates per shard
#define CHUNK 4
#define BCAP 16
#define BSTRIDE 17
#define FTHRESH 12              // post-check cnt<=11, +4/chunk -> <=15 <= BCAP

// ---- workspace layout (bytes) ----
#define OFF_IDX   0u                           // int32 [N_PTS][KK]         = 1 MB
#define OFF_PC    (1u << 20)                   // float4 [N_PTS]            = 256 KB
#define OFF_MA    (OFF_PC + N_PTS * 16u)       // m0 [N][16] / m3 lower half
#define OFF_MB    (OFF_MA + N_PTS * 16u * 4u)  // m1 [N][16] / m3 upper half
#define OFF_MC    (OFF_MB + N_PTS * 16u * 4u)  // m2 [N][32]                = 2 MB
#define OFF_PART  (OFF_MC + N_PTS * 32u * 4u)  // float [1024][64]          = 256 KB
#define OFF_STATS (OFF_PART + 1024u * 64u * 4u)// float [4][64]

// ---------------- prep: pack (x,y,z,d2) ----------------
__global__ __launch_bounds__(256) void prep_kernel(const float* __restrict__ pts,
                                                   float4* __restrict__ pc) {
    int i = blockIdx.x * 256 + threadIdx.x;
    float x = pts[i * 5 + 1], y = pts[i * 5 + 2], z = pts[i * 5 + 3];
    float d2 = __fadd_rn(__fadd_rn(__fmul_rn(x, x), __fmul_rn(y, y)), __fmul_rn(z, z));
    pc[i] = make_float4(x, y, z, d2);
}

// ---------------- branch-free sorting primitives on u64 keys ----------------
__device__ __forceinline__ void ce64(u64& a, u64& b) {
    bool c = b < a;
    u64 t = c ? b : a;
    b = c ? a : b;
    a = t;
}

// sort 8 ascending (Batcher odd-even mergesort, 19 CE)
__device__ __forceinline__ void sort8(u64* b) {
    ce64(b[0], b[1]); ce64(b[2], b[3]); ce64(b[4], b[5]); ce64(b[6], b[7]);
    ce64(b[0], b[2]); ce64(b[1], b[3]); ce64(b[4], b[6]); ce64(b[5], b[7]);
    ce64(b[1], b[2]); ce64(b[5], b[6]);
    ce64(b[0], b[4]); ce64(b[1], b[5]); ce64(b[2], b[6]); ce64(b[3], b[7]);
    ce64(b[2], b[4]); ce64(b[3], b[5]);
    ce64(b[1], b[2]); ce64(b[3], b[4]); ce64(b[5], b[6]);
}

// sort 16 ascending: two sort8 + bitonic merge
__device__ __forceinline__ void sort16(u64 b[16]) {
    sort8(b); sort8(b + 8);
#pragma unroll
    for (int j = 0; j < 8; ++j) ce64(b[j], b[15 - j]);
#pragma unroll
    for (int h = 0; h < 16; h += 8) {
        ce64(b[h + 0], b[h + 4]); ce64(b[h + 1], b[h + 5]);
        ce64(b[h + 2], b[h + 6]); ce64(b[h + 3], b[h + 7]);
        ce64(b[h + 0], b[h + 2]); ce64(b[h + 1], b[h + 3]);
        ce64(b[h + 4], b[h + 6]); ce64(b[h + 5], b[h + 7]);
        ce64(b[h + 0], b[h + 1]); ce64(b[h + 2], b[h + 3]);
        ce64(b[h + 4], b[h + 5]); ce64(b[h + 6], b[h + 7]);
    }
}

// merge two ascending 16-lists, keep smallest 16 ascending in L (B clobbered)
__device__ __forceinline__ void merge16(u64 L[16], u64 B[16]) {
#pragma unroll
    for (int j = 0; j < 8; ++j) {
        u64 a0 = L[j],      b0 = B[15 - j];
        u64 a1 = L[15 - j], b1 = B[j];
        B[j]      = a0 < b0 ? a0 : b0;
        B[15 - j] = a1 < b1 ? a1 : b1;
    }
#pragma unroll
    for (int s = 8; s >= 1; s >>= 1) {
#pragma unroll
        for (int j = 0; j < 16; ++j)
            if (!(j & s)) ce64(B[j], B[j + s]);
    }
#pragma unroll
    for (int j = 0; j < 16; ++j) L[j] = B[j];
}

// monotone key transform helpers (float bits <-> sortable uint)
__device__ __forceinline__ unsigned fkey(unsigned u) {
    return u ^ ((unsigned)(((int)u) >> 31) | 0x80000000u);
}
__device__ __forceinline__ unsigned fkey_inv(unsigned k32) {
    unsigned xv = 0x80000000u | ((~((unsigned)(((int)k32) >> 31))) >> 1);
    return k32 ^ xv; // sentinel 0xFFFFFFFF -> 0x7FFFFFFF (uint > +inf bits)
}

// flush buffered raw (floatbits<<32|idx) entries: transform to monotone keys,
// sort (pad to 16), merge into L. Returns float-BITS of new 16th-best dist.
__device__ __forceinline__ unsigned flush16(u64 L[16], const u64* buf, int& cnt) {
    u64 b[16];
#pragma unroll
    for (int e = 0; e < 16; ++e) {
        u64 raw = (e < BCAP) ? buf[e] : 0ULL;
        u64 key = ((u64)fkey((unsigned)(raw >> 32)) << 32) | (raw & 0xffffffffULL);
        b[e] = (e < cnt) ? key : ~0ULL;
    }
    cnt = 0;
    sort16(b);
    merge16(L, b);
    return fkey_inv((unsigned)(L[15] >> 32));
}

// ---------------- exact KNN (top-16 smallest dist, ties -> lower index) ----------------
// Shared per-query threshold: tauS[q] = min over the query's 16 shards of each
// shard's current 16th-best dist (float bits; dists >= 0 so uint order == float
// order). Rejecting dist > tau is exact: >=16 candidates <= tau exist.
__global__ __launch_bounds__(256, 4) void knn_kernel(const float4* __restrict__ pc,
                                                     int* __restrict__ idx) {
    // [0, 256*17) u64 lane buffers; tree phase reuses [0, 128*17)
    __shared__ u64 smem[256 * BSTRIDE]; // 34,816 B -> 4 blocks/CU
    __shared__ unsigned tauS[QPB];

    const int tid = threadIdx.x;
    const int q = tid & (QPB - 1);
    const int s = tid >> 4;
    const int n = blockIdx.x * QPB + q;
    const int base = (n >= HALF_N) ? HALF_N : 0;
    const float4 p = pc[n];

    if (tid < QPB) tauS[tid] = 0x7f800000u; // +inf bits

    u64* buf = &smem[tid * BSTRIDE];
    int cnt = 0;
    const int c0 = base + s * MCAND;

    // ---- seed: exact sorted top-16 of the shard's first 16 candidates ----
    u64 L[16];
#pragma unroll
    for (int j = 0; j < 16; ++j) {
        const int ci = c0 + j;
        const float4 cp = pc[ci];
        float dot = __fadd_rn(__fadd_rn(__fmul_rn(p.x, cp.x), __fmul_rn(p.y, cp.y)),
                              __fmul_rn(p.z, cp.z));
        float dist = __fsub_rn(__fadd_rn(p.w, cp.w), __fmul_rn(2.0f, dot));
        L[j] = ((u64)fkey(__float_as_uint(dist)) << 32) | (unsigned)ci;
    }
    sort16(L);
    atomicMin(&tauS[q], fkey_inv((unsigned)(L[15] >> 32)));
    __syncthreads(); // all seed taus visible

    // ---- main scan ----
#pragma unroll 1
    for (int t0 = 16; t0 < MCAND; t0 += CHUNK) {
        const float tauf = __uint_as_float(((volatile unsigned*)tauS)[q]);
#pragma unroll
        for (int dt = 0; dt < CHUNK; ++dt) {
            const int ci = c0 + t0 + dt;
            const float4 cp = pc[ci]; // uniform per 16-lane group -> broadcast
            float dot = __fadd_rn(__fadd_rn(__fmul_rn(p.x, cp.x), __fmul_rn(p.y, cp.y)),
                                  __fmul_rn(p.z, cp.z));
            float dist = __fsub_rn(__fadd_rn(p.w, cp.w), __fmul_rn(2.0f, dot));
            if (!(dist > tauf)) { // ties admitted; exact select at flush
                buf[cnt] = ((u64)__float_as_uint(dist) << 32) | (unsigned)ci;
                ++cnt;
            }
        }
        if (__any(cnt >= FTHRESH)) {
            unsigned tb = flush16(L, buf, cnt);
            atomicMin(&tauS[q], tb);
        }
        // invariant: cnt <= 11 after check, +4 per chunk -> <= 15 <= BCAP
    }
    flush16(L, buf, cnt);

    // ---- cross-shard merge tree (writer-half lists staged in reused smem) ----
    __syncthreads(); // buffers dead
    for (int step = SHARDS / 2; step >= 1; step >>= 1) {
        if (s >= step && s < 2 * step) {
#pragma unroll
            for (int j = 0; j < 16; ++j) smem[((s - step) * QPB + q) * 17 + j] = L[j];
        }
        __syncthreads();
        if (s < step) {
            u64 B[16];
#pragma unroll
            for (int j = 0; j < 16; ++j) B[j] = smem[(s * QPB + q) * 17 + j];
            merge16(L, B);
        }
        __syncthreads();
    }

    if (s == 0) {
#pragma unroll
        for (int j = 0; j < 16; ++j) idx[n * KK + j] = (int)(L[j] & 0xffffffffULL);
    }
}

// ============ per-layer conv: h once -> {part sums, raw per-point max} ============
// MODE 0: xin = pts (stride 5, offset 1, raw). MODE 1: xin = m_prev, apply
// relu(fma(., A, B2)) of the PREVIOUS layer on the fly (A>0, so
// max-then-affine == affine-then-max; relu monotone).
template <int IN_C, int OUT_C, int MODE>
__global__ __launch_bounds__(256) void convS_kernel(const float* __restrict__ xin,
                                                    const float* __restrict__ statsPrev,
                                                    const int* __restrict__ idxg,
                                                    const float* __restrict__ W,
                                                    const float* __restrict__ bb,
                                                    float* __restrict__ part,
                                                    float* __restrict__ mout) {
    constexpr int RED = 256 / OUT_C;
    __shared__ float hbuf[OUT_C][257];
    __shared__ float pr1[OUT_C][RED + 1];
    __shared__ float pr2[OUT_C][RED + 1];
    __shared__ float2 sAB[IN_C];

    const int tid = threadIdx.x;
    const int gt = blockIdx.x * 256 + tid;
    const int n = gt >> 4;

    if (MODE == 1) {
        if (tid < IN_C) sAB[tid] = make_float2(statsPrev[tid], statsPrev[32 + tid]);
        __syncthreads();
    }

    float xn[IN_C], dx[IN_C];
    const int j = idxg[gt];
    if (MODE == 0) {
        const float* rn = xin + n * 5 + 1;
        const float* rj = xin + j * 5 + 1;
#pragma unroll
        for (int e = 0; e < IN_C; ++e) xn[e] = rn[e];
#pragma unroll
        for (int e = 0; e < IN_C; ++e) dx[e] = rj[e] - xn[e];
    } else {
        const float4* rn = (const float4*)(xin + n * IN_C);
        const float4* rj = (const float4*)(xin + j * IN_C);
#pragma unroll
        for (int e4 = 0; e4 < IN_C / 4; ++e4) {
            float4 a = rn[e4];
            float4 bq = rj[e4];
            float av[4] = {a.x, a.y, a.z, a.w};
            float bv[4] = {bq.x, bq.y, bq.z, bq.w};
#pragma unroll
            for (int u = 0; u < 4; ++u) {
                float2 ab = sAB[4 * e4 + u];
                float xv = fmaxf(fmaf(av[u], ab.x, ab.y), 0.f);
                float jv = fmaxf(fmaf(bv[u], ab.x, ab.y), 0.f);
                xn[4 * e4 + u] = xv;
                dx[4 * e4 + u] = jv - xv;
            }
        }
    }

    float h[OUT_C];
#pragma unroll
    for (int c = 0; c < OUT_C; ++c) {
        float acc = bb[c];
#pragma unroll
        for (int e = 0; e < IN_C; ++e) acc = fmaf(W[c * 2 * IN_C + e], xn[e], acc);
#pragma unroll
        for (int e = 0; e < IN_C; ++e) acc = fmaf(W[c * 2 * IN_C + IN_C + e], dx[e], acc);
        h[c] = acc;
    }

    // ---- stage h to LDS once; sums and max both read from hbuf ----
#pragma unroll
    for (int c = 0; c < OUT_C; ++c) hbuf[c][tid] = h[c];
    __syncthreads();
    {
        const int c2 = tid & (OUT_C - 1);
        const int ch = tid / OUT_C;
        float s1 = 0.f, s2 = 0.f;
#pragma unroll
        for (int i = 0; i < OUT_C; ++i) {
            float hh = hbuf[c2][ch * OUT_C + i];
            s1 += hh; s2 += hh * hh;
        }
        pr1[c2][ch] = s1;
        pr2[c2][ch] = s2;
    }
    __syncthreads();
    if (tid < OUT_C) {
        float t1 = 0.f, t2 = 0.f;
#pragma unroll
        for (int k = 0; k < RED; ++k) { t1 += pr1[tid][k]; t2 += pr2[tid][k]; }
        part[blockIdx.x * 64 + tid]      = t1;
        part[blockIdx.x * 64 + 32 + tid] = t2;
    }

    // ---- raw max over K=16 from hbuf: one thread per (n_local, c) ----
    {
        const int n0 = blockIdx.x * 16;
        constexpr int ITER = OUT_C / 16;
#pragma unroll
        for (int r = 0; r < ITER; ++r) {
            const int c = tid & (OUT_C - 1);
            const int nl = (tid / OUT_C) + r * (256 / OUT_C);
            float m = hbuf[c][nl * 16];
#pragma unroll
            for (int k = 1; k < 16; ++k) m = fmaxf(m, hbuf[c][nl * 16 + k]);
            mout[(n0 + nl) * OUT_C + c] = m;
        }
    }
}

// ---------------- finalize: part -> A[c]=rs*g, B2[c]=t-mu*A ----------------
template <int OUT_C>
__global__ __launch_bounds__(256) void finalize_kernel(const float* __restrict__ part,
                                                       const float* __restrict__ g,
                                                       const float* __restrict__ t,
                                                       float* __restrict__ statsL) {
    __shared__ float red[4][64];
    __shared__ float tot[64];
    const int tid = threadIdx.x;
    const int c2 = tid & 63, ch = tid >> 6;
    float s = 0.f;
    for (int bk = ch * 256; bk < ch * 256 + 256; ++bk) s += part[bk * 64 + c2];
    red[ch][c2] = s;
    __syncthreads();
    if (tid < 64) tot[tid] = red[0][tid] + red[1][tid] + red[2][tid] + red[3][tid];
    __syncthreads();
    if (tid < OUT_C) {
        const float inv = 1.0f / (float)NK;
        float mu  = tot[tid] * inv;
        float var = tot[32 + tid] * inv - mu * mu;
        float rs  = 1.0f / sqrtf(var + EPSV);
        float A   = rs * g[tid];
        statsL[tid]      = A;
        statsL[32 + tid] = t[tid] - mu * A;
    }
}

// ---- fused finalize(layer3) + apply: every block redundantly reduces part
// (deterministic fixed order), then applies relu(affine(m3)) to its slice ----
__global__ __launch_bounds__(256) void finapply_kernel(const float* __restrict__ part,
                                                       const float* __restrict__ g,
                                                       const float* __restrict__ t,
                                                       const float* __restrict__ m,
                                                       float* __restrict__ out) {
    __shared__ float red[4][64];
    __shared__ float tot[64];
    __shared__ float sA[32], sB[32];
    const int tid = threadIdx.x;
    const int c2 = tid & 63, ch = tid >> 6;
    float s = 0.f;
    for (int bk = ch * 256; bk < ch * 256 + 256; ++bk) s += part[bk * 64 + c2];
    red[ch][c2] = s;
    __syncthreads();
    if (tid < 64) tot[tid] = red[0][tid] + red[1][tid] + red[2][tid] + red[3][tid];
    __syncthreads();
    if (tid < 32) {
        const float inv = 1.0f / (float)NK;
        float mu  = tot[tid] * inv;
        float var = tot[32 + tid] * inv - mu * mu;
        float rs  = 1.0f / sqrtf(var + EPSV);
        float A   = rs * g[tid];
        sA[tid] = A;
        sB[tid] = t[tid] - mu * A;
    }
    __syncthreads();
    const int base = blockIdx.x * 2048 + tid;
#pragma unroll
    for (int r = 0; r < 8; ++r) {
        const int i = base + r * 256;
        float4 mv = ((const float4*)m)[i];
        const int c0 = (i * 4) & 31;
        float4 o;
        o.x = fmaxf(fmaf(mv.x, sA[c0 + 0], sB[c0 + 0]), 0.f);
        o.y = fmaxf(fmaf(mv.y, sA[c0 + 1], sB[c0 + 1]), 0.f);
        o.z = fmaxf(fmaf(mv.z, sA[c0 + 2], sB[c0 + 2]), 0.f);
        o.w = fmaxf(fmaf(mv.w, sA[c0 + 3], sB[c0 + 3]), 0.f);
        ((float4*)out)[i] = o;
    }
}

extern "C" void kernel_launch(void* const* d_in, const int* in_sizes, int n_in,
                              void* d_out, int out_size, void* d_ws, size_t ws_size,
                              hipStream_t stream) {
    const float* pts = (const float*)d_in[0];
    const float* Wl[4], *bl[4], *gl[4], *tl[4];
    for (int l = 0; l < 4; ++l) {
        Wl[l] = (const float*)d_in[1 + 4 * l + 0];
        bl[l] = (const float*)d_in[1 + 4 * l + 1];
        gl[l] = (const float*)d_in[1 + 4 * l + 2];
        tl[l] = (const float*)d_in[1 + 4 * l + 3];
    }
    char* ws = (char*)d_ws;
    int*    idx   = (int*)(ws + OFF_IDX);
    float4* pc    = (float4*)(ws + OFF_PC);
    float*  m0    = (float*)(ws + OFF_MA); // [N][16]
    float*  m1    = (float*)(ws + OFF_MB); // [N][16]
    float*  m2    = (float*)(ws + OFF_MC); // [N][32]
    float*  m3    = (float*)(ws + OFF_MA); // [N][32] reuses MA|MB (m0,m1 dead)
    float*  part  = (float*)(ws + OFF_PART);
    float*  stats = (float*)(ws + OFF_STATS); // [4][64]
    float*  out   = (float*)d_out;

    prep_kernel<<<N_PTS / 256, 256, 0, stream>>>(pts, pc);
    knn_kernel<<<N_PTS / QPB, 256, 0, stream>>>(pc, idx);

    const int GA = NK / 256; // 1024 blocks

    // layer 0: 4 -> 16 (raw pts input)
    convS_kernel<4, 16, 0><<<GA, 256, 0, stream>>>(pts, nullptr, idx, Wl[0], bl[0], part, m0);
    finalize_kernel<16><<<1, 256, 0, stream>>>(part, gl[0], tl[0], stats + 0);

    // layer 1: 16 -> 16 (m0 + layer-0 affine on the fly)
    convS_kernel<16, 16, 1><<<GA, 256, 0, stream>>>(m0, stats + 0, idx, Wl[1], bl[1], part, m1);
    finalize_kernel<16><<<1, 256, 0, stream>>>(part, gl[1], tl[1], stats + 64);

    // layer 2: 16 -> 32
    convS_kernel<16, 32, 1><<<GA, 256, 0, stream>>>(m1, stats + 64, idx, Wl[2], bl[2], part, m2);
    finalize_kernel<32><<<1, 256, 0, stream>>>(part, gl[2], tl[2], stats + 128);

    // layer 3: 32 -> 32 (writes m3 over MA|MB; m0/m1 dead)
    convS_kernel<32, 32, 1><<<GA, 256, 0, stream>>>(m2, stats + 128, idx, Wl[3], bl[3], part, m3);

    // fused finalize(layer3) + out = relu(affine(m3))
    finapply_kernel<<<64, 256, 0, stream>>>(part, gl[3], tl[3], m3, out);
}